// Round 9
// baseline (1037.208 us; speedup 1.0000x reference)
//
#include <hip/hip_runtime.h>
#include <hip/hip_bf16.h>
#include <stdint.h>
#include <stddef.h>

#define NN 100000
#define NE 300000
#define FINDIM 128
#define HD 256
#define NG 4000
#define NLAYER 5
#define MPAD 100096   // multiple of 32; pad rows kept == 0.0f always
#define NT (MPAD/32)  // 3128 m-tiles of 32 rows
#define MG 512        // m-groups; grid = 2*MG = 1024 (4 blocks/CU resident)

typedef __attribute__((ext_vector_type(8))) short bf8;
typedef __attribute__((ext_vector_type(4))) float f4;

#define FENCE() __asm__ volatile("" ::: "memory")
#define WAITVM0() __asm__ volatile("s_waitcnt vmcnt(0)" ::: "memory")
#define WAITVM4() __asm__ volatile("s_waitcnt vmcnt(4)" ::: "memory")
#define WAITVM6() __asm__ volatile("s_waitcnt vmcnt(6)" ::: "memory")
#define WAITVM8() __asm__ volatile("s_waitcnt vmcnt(8)" ::: "memory")
#define WAITLGKM() __asm__ volatile("s_waitcnt lgkmcnt(0)" ::: "memory")
#define BARRIER() do { FENCE(); __builtin_amdgcn_s_barrier(); FENCE(); } while(0)

__device__ __forceinline__ unsigned short f2bf(float f){
  union { float f; unsigned u; } uf; uf.f = f;
  unsigned r = uf.u + 0x7fffu + ((uf.u >> 16) & 1u);
  return (unsigned short)(r >> 16);
}
__device__ __forceinline__ float bf2f(unsigned short h){
  union { unsigned u; float f; } uf; uf.u = ((unsigned)h) << 16; return uf.f;
}

__device__ __forceinline__ void gload16(const void* g, void* l){
  __builtin_amdgcn_global_load_lds((const __attribute__((address_space(1))) void*)g,
                                   (__attribute__((address_space(3))) void*)l, 16, 0, 0);
}

// ---------------- zero fill ----------------
__global__ void k_zero(int* __restrict__ p, int n){
  int i = blockIdx.x*256 + threadIdx.x;
  if(i < n) p[i] = 0;
}

// ---------------- CSR build ----------------
__global__ void k_count(const int* __restrict__ ei, int* __restrict__ counts){
  int e = blockIdx.x*256 + threadIdx.x;
  if(e < NE) atomicAdd(&counts[ei[NE + e]], 1);
}

__global__ void k_scan_partial(const int* __restrict__ counts, int* __restrict__ partials){
  __shared__ int sw[4];
  int b = blockIdx.x, t = threadIdx.x;
  int base = b*1024 + t*4;
  int s = 0;
  #pragma unroll
  for(int j=0;j<4;j++){ int i = base+j; if(i < NN) s += counts[i]; }
  #pragma unroll
  for(int d=1; d<64; d<<=1) s += __shfl_xor(s, d, 64);
  if((t & 63) == 0) sw[t>>6] = s;
  __syncthreads();
  if(t == 0) partials[b] = sw[0]+sw[1]+sw[2]+sw[3];
}

__global__ void k_scan_tot(int* __restrict__ partials, int* __restrict__ offsets, int nb){
  __shared__ int sm[128];
  int t = threadIdx.x;
  int v = (t < nb) ? partials[t] : 0;
  sm[t] = v; __syncthreads();
  for(int d=1; d<128; d<<=1){
    int x = 0;
    if(t >= d) x = sm[t-d];
    __syncthreads();
    sm[t] += x;
    __syncthreads();
  }
  if(t < nb) partials[t] = sm[t] - v;   // exclusive
  if(t == 127) offsets[NN] = sm[127];   // total == NE
}

__global__ void k_scan_final(const int* __restrict__ counts, const int* __restrict__ partials,
                             int* __restrict__ offsets, int* __restrict__ cursor){
  __shared__ int wsum[4];
  int b = blockIdx.x, t = threadIdx.x;
  int base = b*1024 + t*4;
  int c[4]; int ts = 0;
  #pragma unroll
  for(int j=0;j<4;j++){ int i = base+j; c[j] = (i < NN) ? counts[i] : 0; ts += c[j]; }
  int lane = t & 63;
  int inc = ts;
  #pragma unroll
  for(int d=1; d<64; d<<=1){ int x = __shfl_up(inc, d, 64); if(lane >= d) inc += x; }
  if(lane == 63) wsum[t>>6] = inc;
  __syncthreads();
  int woff = 0;
  for(int w2=0; w2<(t>>6); w2++) woff += wsum[w2];
  int excl = partials[b] + woff + inc - ts;
  #pragma unroll
  for(int j=0;j<4;j++){
    int i = base+j;
    if(i < NN){ offsets[i] = excl; cursor[i] = excl; excl += c[j]; }
  }
}

__global__ void k_fill(const int* __restrict__ ei, int* __restrict__ cursor, int* __restrict__ eidx){
  int e = blockIdx.x*256 + threadIdx.x;
  if(e < NE){
    int d = ei[NE + e];
    int pos = atomicAdd(&cursor[d], 1);
    eidx[pos] = ei[e];
  }
}

// ---------------- weight transpose/convert ----------------
__global__ void k_wt(const float* __restrict__ src, unsigned short* __restrict__ dst, int K, int Ncols){
  int l = blockIdx.y;
  size_t base = (size_t)l * K * Ncols;
  int i = blockIdx.x*256 + threadIdx.x;
  if(i < K*Ncols){
    int k = i / Ncols, n = i % Ncols;
    dst[base + (size_t)n*K + k] = f2bf(src[base + i]);
  }
}

// ---------------- GEMM, B-in-regs + manual per-tile DMA pipeline (4 blocks/CU) ----------------
// Grid 2*MG: nh = b&1, mg = b>>1. Block 256 thr / 4 waves; wave tile 32m x 32n.
// A staged per 32x256 tile (16 KB), 2 buffers; DMA for tile t+2 issued right after the
// post-MFMA barrier (overlaps epilogue). Steady-state vmcnt(8) keeps next DMA in flight.
// TRANS: one-pass in-LDS BN transform. Two-phase epilogue halves Cs -> LDS 39.4 KB.
template<int TRANS, bool RELUOUT, bool STATS>
__global__ __launch_bounds__(256, 4) void k_gemmb(
    const unsigned short* __restrict__ A, const unsigned short* __restrict__ Bt,
    const float* __restrict__ bias, const float* __restrict__ preS,
    const float* __restrict__ preT, unsigned short* __restrict__ C,
    float* __restrict__ stats)
{
  __shared__ __align__(16) unsigned short As[2][8192];   // 32 KB
  __shared__ __align__(16) unsigned short Cs[2][1152];   // 4.5 KB (two-phase epilogue)
  __shared__ __align__(16) float SP[512];                // 2 KB
  const int t = threadIdx.x;
  const int lane = t & 63, w = t >> 6;
  const int q = lane >> 4, ln = lane & 15;
  const int nh = blockIdx.x & 1;
  const int mg = blockIdx.x >> 1;
  const int nbase = nh*128 + w*32;

  if(TRANS){ SP[t] = preS[t]; SP[256 + t] = preT[t]; WAITLGKM(); }

  // B fragments resident in registers (L2-resident 128 KB weight)
  bf8 bb[2][8];
  #pragma unroll
  for(int nf=0; nf<2; nf++)
    #pragma unroll
    for(int s=0; s<8; s++)
      bb[nf][s] = *(const bf8*)(Bt + (size_t)(nbase + nf*16 + ln)*HD + s*32 + q*8);

  float bv[2];
  #pragma unroll
  for(int nf=0; nf<2; nf++) bv[nf] = bias[nbase + nf*16 + ln];

  auto issueA = [&](int mt, int b){
    const int m0 = mt*32;
    #pragma unroll
    for(int j=0; j<4; j++){
      int slot = j*256 + t;
      int row = slot >> 5, p = slot & 31;
      int c = p ^ (row & 7);
      gload16(A + (size_t)(m0 + row)*HD + c*8, &As[b][(j*256 + w*64)*8]);
    }
  };

  float sacc[2] = {0.f, 0.f}, ssacc[2] = {0.f, 0.f};

  issueA(mg, 0);
  issueA(mg + MG, 1);           // mg+MG < NT always (mg<512, NT=3128)

  int tc = 0;
  for(int mt = mg; mt < NT; mt += MG, tc++){
    const bool last = (mt + MG >= NT);
    // wait DMA(tc) landed; keep later DMA + recent stores in flight
    if(last)           WAITVM0();
    else if(tc == 0)   WAITVM4();
    else if(tc == 1)   WAITVM6();
    else               WAITVM8();
    BARRIER();                          // all waves have tile tc in LDS

    unsigned short* Ab = &As[tc&1][0];
    const int m0 = mt*32;
    const bool padt = (m0 >= NN);

    if(TRANS){
      // one-pass in-LDS BN+ReLU transform (or zero pad tiles)
      #pragma unroll
      for(int j=0; j<4; j++){
        int slot = j*256 + t;
        if(padt){
          *(uint4*)&Ab[slot*8] = (uint4){0u,0u,0u,0u};
        } else {
          int row = slot >> 5, p = slot & 31;
          int c = p ^ (row & 7);
          uint4 u = *(const uint4*)&Ab[slot*8];
          f4 s0 = *(const f4*)&SP[c*8];
          f4 s1 = *(const f4*)&SP[c*8 + 4];
          f4 t0 = *(const f4*)&SP[256 + c*8];
          f4 t1 = *(const f4*)&SP[256 + c*8 + 4];
          float scv[8] = {s0.x,s0.y,s0.z,s0.w,s1.x,s1.y,s1.z,s1.w};
          float shv[8] = {t0.x,t0.y,t0.z,t0.w,t1.x,t1.y,t1.z,t1.w};
          unsigned short* us = (unsigned short*)&u;
          #pragma unroll
          for(int e=0; e<8; e++){
            float v = bf2f(us[e]);
            v = fmaxf(fmaf(scv[e], v, shv[e]), 0.f);
            us[e] = f2bf(v);
          }
          *(uint4*)&Ab[slot*8] = u;
        }
      }
      WAITLGKM();
      BARRIER();                        // transformed tile visible to all waves
    }

    f4 acc[2][2];
    #pragma unroll
    for(int i=0;i<2;i++)
      #pragma unroll
      for(int j=0;j<2;j++) acc[i][j] = (f4){0.f,0.f,0.f,0.f};

    #pragma unroll
    for(int s=0; s<8; s++){
      bf8 af[2];
      #pragma unroll
      for(int mi=0; mi<2; mi++){
        int row = mi*16 + ln;
        int p = (s*4 + q) ^ (row & 7);
        af[mi] = *(const bf8*)&Ab[row*256 + p*8];
      }
      #pragma unroll
      for(int mi=0; mi<2; mi++)
        #pragma unroll
        for(int nf=0; nf<2; nf++)
          acc[mi][nf] = __builtin_amdgcn_mfma_f32_16x16x32_bf16(af[mi], bb[nf][s], acc[mi][nf], 0, 0, 0);
    }

    // all waves done reading buf[tc&1] (MFMA consumed reads) -> re-DMA it now,
    // overlapping the DMA with stats + epilogue below
    BARRIER();
    if(mt + 2*MG < NT) issueA(mt + 2*MG, tc&1);

    if(STATS){
      #pragma unroll
      for(int nf=0; nf<2; nf++)
        #pragma unroll
        for(int mi=0; mi<2; mi++)
          #pragma unroll
          for(int r=0; r<4; r++){
            float v = acc[mi][nf][r];
            sacc[nf] += v; ssacc[nf] = fmaf(v, v, ssacc[nf]);
          }
    }

    // two-phase epilogue: waves 0,1 then waves 2,3 through half-size Cs
    #pragma unroll
    for(int ph=0; ph<2; ph++){
      if((w >> 1) == ph){
        unsigned short* wsc = &Cs[w & 1][0];   // 32 rows x 36
        #pragma unroll
        for(int mi=0; mi<2; mi++)
          #pragma unroll
          for(int nf=0; nf<2; nf++)
            #pragma unroll
            for(int r=0; r<4; r++){
              float v = acc[mi][nf][r] + bv[nf];
              if(RELUOUT) v = fmaxf(v, 0.f);
              if(padt) v = 0.f;
              wsc[(mi*16 + q*4 + r)*36 + nf*16 + ln] = f2bf(v);
            }
        int r2 = lane >> 1, ch = lane & 1;
        size_t cb = (size_t)(m0 + r2)*HD + nh*128 + w*32;
        uint4 u0 = *(const uint4*)&wsc[r2*36 + ch*8];
        uint4 u1 = *(const uint4*)&wsc[r2*36 + (ch+2)*8];
        *(uint4*)&C[cb + ch*8]     = u0;
        *(uint4*)&C[cb + (ch+2)*8] = u1;
      }
      if(ph == 0) BARRIER();
    }
  }

  if(STATS){
    #pragma unroll
    for(int nf=0; nf<2; nf++){
      float s = sacc[nf], ss = ssacc[nf];
      s  += __shfl_xor(s, 16, 64);  s  += __shfl_xor(s, 32, 64);
      ss += __shfl_xor(ss, 16, 64); ss += __shfl_xor(ss, 32, 64);
      if(q == 0){
        int gn = nbase + nf*16 + ln;
        atomicAdd(&stats[gn], s);
        atomicAdd(&stats[HD + gn], ss);
      }
    }
  }
}

// ---------------- input projection (f32 A, K=128), B-in-registers ----------------
__global__ __launch_bounds__(256, 3) void k_gemmb_in(
    const float* __restrict__ A, const unsigned short* __restrict__ Bt,
    const float* __restrict__ bias, unsigned short* __restrict__ C)
{
  __shared__ __align__(16) unsigned short As[4096];      // 32 rows x 128 k = 8 KB
  __shared__ __align__(16) unsigned short Cs[4][1152];
  const int t = threadIdx.x;
  const int lane = t & 63, w = t >> 6;
  const int q = lane >> 4, ln = lane & 15;
  const int nh = blockIdx.x & 1;
  const int mg = blockIdx.x >> 1;
  const int nbase = nh*128 + w*32;

  bf8 bb[2][4];
  #pragma unroll
  for(int nf=0; nf<2; nf++)
    #pragma unroll
    for(int s=0; s<4; s++)
      bb[nf][s] = *(const bf8*)(Bt + (size_t)(nbase + nf*16 + ln)*FINDIM + s*32 + q*8);

  float bv[2];
  #pragma unroll
  for(int nf=0; nf<2; nf++) bv[nf] = bias[nbase + nf*16 + ln];

  for(int mt = mg; mt < NT; mt += MG){
    const int m0 = mt*32;
    const bool padt = (m0 >= NN);
    __syncthreads();
    #pragma unroll
    for(int j=0; j<2; j++){
      int slot = j*256 + t;
      int row = slot >> 4, p = slot & 15;
      int c = p ^ (row & 7);
      int gm = m0 + row;
      f4 v0 = (f4){0.f,0.f,0.f,0.f}, v1 = (f4){0.f,0.f,0.f,0.f};
      if(gm < NN){
        v0 = *(const f4*)&A[(size_t)gm*FINDIM + c*8];
        v1 = *(const f4*)&A[(size_t)gm*FINDIM + c*8 + 4];
      }
      ushort4 a0, a1;
      a0.x = f2bf(v0.x); a0.y = f2bf(v0.y); a0.z = f2bf(v0.z); a0.w = f2bf(v0.w);
      a1.x = f2bf(v1.x); a1.y = f2bf(v1.y); a1.z = f2bf(v1.z); a1.w = f2bf(v1.w);
      *(ushort4*)&As[row*128 + p*8]     = a0;
      *(ushort4*)&As[row*128 + p*8 + 4] = a1;
    }
    __syncthreads();

    f4 acc[2][2];
    #pragma unroll
    for(int i=0;i<2;i++)
      #pragma unroll
      for(int j=0;j<2;j++) acc[i][j] = (f4){0.f,0.f,0.f,0.f};

    #pragma unroll
    for(int s=0; s<4; s++){
      bf8 af[2];
      #pragma unroll
      for(int mi=0; mi<2; mi++){
        int row = mi*16 + ln;
        int p = (s*4 + q) ^ (row & 7);
        af[mi] = *(const bf8*)&As[row*128 + p*8];
      }
      #pragma unroll
      for(int mi=0; mi<2; mi++)
        #pragma unroll
        for(int nf=0; nf<2; nf++)
          acc[mi][nf] = __builtin_amdgcn_mfma_f32_16x16x32_bf16(af[mi], bb[nf][s], acc[mi][nf], 0, 0, 0);
    }

    unsigned short* wsc = &Cs[w][0];
    #pragma unroll
    for(int mi=0; mi<2; mi++)
      #pragma unroll
      for(int nf=0; nf<2; nf++)
        #pragma unroll
        for(int r=0; r<4; r++){
          float v = fmaxf(acc[mi][nf][r] + bv[nf], 0.f);
          if(padt) v = 0.f;
          wsc[(mi*16 + q*4 + r)*36 + nf*16 + ln] = f2bf(v);
        }
    int r2 = lane >> 1, ch = lane & 1;
    size_t cb = (size_t)(m0 + r2)*HD + nh*128 + w*32;
    uint4 u0 = *(const uint4*)&wsc[r2*36 + ch*8];
    uint4 u1 = *(const uint4*)&wsc[r2*36 + (ch+2)*8];
    *(uint4*)&C[cb + ch*8]     = u0;
    *(uint4*)&C[cb + (ch+2)*8] = u1;
  }
}

// ---------------- BN finalize (bias folded: stats are bias-free raw sums) ----------------
__global__ void k_bnfin(const float* __restrict__ cs, const float* __restrict__ bias,
                        const float* __restrict__ g, const float* __restrict__ be,
                        float* __restrict__ sc, float* __restrict__ sh){
  int c = threadIdx.x;
  float m0 = cs[c] * (1.0f/NN);
  float mean = m0 + bias[c];
  float var  = cs[HD + c] * (1.0f/NN) - m0*m0;
  float s = g[c] * rsqrtf(var + 1e-5f);
  sc[c] = s;
  sh[c] = be[c] - mean*s;
}

// ---------------- aggregation ----------------
__device__ __forceinline__ f4 act4(ushort4 uv, f4 s4, f4 t4, int ident){
  f4 u;
  u.x = bf2f(uv.x); u.y = bf2f(uv.y); u.z = bf2f(uv.z); u.w = bf2f(uv.w);
  if(!ident){
    u.x = fmaxf(fmaf(s4.x, u.x, t4.x), 0.f);
    u.y = fmaxf(fmaf(s4.y, u.y, t4.y), 0.f);
    u.z = fmaxf(fmaf(s4.z, u.z, t4.z), 0.f);
    u.w = fmaxf(fmaf(s4.w, u.w, t4.w), 0.f);
  }
  return u;
}

__global__ __launch_bounds__(256) void k_agg(const unsigned short* __restrict__ src,
    unsigned short* __restrict__ dst,
    const int* __restrict__ offs, const int* __restrict__ eidx,
    const float* __restrict__ eps, int l,
    const float* __restrict__ sc, const float* __restrict__ sh, int ident)
{
  int wv = threadIdx.x >> 6;
  int n = blockIdx.x*4 + wv;
  if(n >= NN) return;
  int lane = threadIdx.x & 63;
  int c = lane << 2;
  f4 s4 = (f4){0.f,0.f,0.f,0.f}, t4 = (f4){0.f,0.f,0.f,0.f};
  if(!ident){ s4 = *(const f4*)(sc + c); t4 = *(const f4*)(sh + c); }
  float ep = 1.f + eps[l];
  f4 a = act4(*(const ushort4*)(src + (size_t)n*HD + c), s4, t4, ident);
  f4 acc;
  acc.x = ep*a.x; acc.y = ep*a.y; acc.z = ep*a.z; acc.w = ep*a.w;
  int lo = offs[n], hi = offs[n+1];
  for(int base = lo; base < hi; base += 64){
    int rem = hi - base; if(rem > 64) rem = 64;
    int idx = 0;
    if(base + lane < hi) idx = eidx[base + lane];
    int j = 0;
    for(; j + 4 <= rem; j += 4){
      int s0 = __shfl(idx, j, 64),   s1 = __shfl(idx, j+1, 64);
      int s2 = __shfl(idx, j+2, 64), s3 = __shfl(idx, j+3, 64);
      ushort4 u0 = *(const ushort4*)(src + (size_t)s0*HD + c);
      ushort4 u1 = *(const ushort4*)(src + (size_t)s1*HD + c);
      ushort4 u2 = *(const ushort4*)(src + (size_t)s2*HD + c);
      ushort4 u3 = *(const ushort4*)(src + (size_t)s3*HD + c);
      f4 a0 = act4(u0, s4, t4, ident), a1 = act4(u1, s4, t4, ident);
      f4 a2 = act4(u2, s4, t4, ident), a3 = act4(u3, s4, t4, ident);
      acc.x += (a0.x + a1.x) + (a2.x + a3.x);
      acc.y += (a0.y + a1.y) + (a2.y + a3.y);
      acc.z += (a0.z + a1.z) + (a2.z + a3.z);
      acc.w += (a0.w + a1.w) + (a2.w + a3.w);
    }
    for(; j < rem; j++){
      int s0 = __shfl(idx, j, 64);
      f4 a0 = act4(*(const ushort4*)(src + (size_t)s0*HD + c), s4, t4, ident);
      acc.x += a0.x; acc.y += a0.y; acc.z += a0.z; acc.w += a0.w;
    }
  }
  ushort4 o;
  o.x = f2bf(acc.x); o.y = f2bf(acc.y); o.z = f2bf(acc.z); o.w = f2bf(acc.w);
  *(ushort4*)(dst + (size_t)n*HD + c) = o;
}

// ---------------- pooling ----------------
__device__ __forceinline__ int lowb(const int* __restrict__ arr, int n, int key){
  int lo = 0, hi = n;
  while(lo < hi){ int mid = (lo + hi) >> 1; if(arr[mid] < key) lo = mid + 1; else hi = mid; }
  return lo;
}

__global__ __launch_bounds__(256) void k_pool(const unsigned short* __restrict__ src,
    const int* __restrict__ batch,
    const float* __restrict__ sc, const float* __restrict__ sh, float* __restrict__ pooled)
{
  int wv = threadIdx.x >> 6;
  int g = blockIdx.x*4 + wv;
  if(g >= NG) return;
  int lane = threadIdx.x & 63;
  int c = lane << 2;
  int lo = lowb(batch, NN, g);
  int hi = lowb(batch, NN, g+1);
  f4 s4 = *(const f4*)(sc + c);
  f4 t4 = *(const f4*)(sh + c);
  f4 acc = (f4){0.f,0.f,0.f,0.f};
  for(int n=lo; n<hi; n++){
    ushort4 uv = *(const ushort4*)(src + (size_t)n*HD + c);
    acc.x += fmaxf(fmaf(s4.x, bf2f(uv.x), t4.x), 0.f);
    acc.y += fmaxf(fmaf(s4.y, bf2f(uv.y), t4.y), 0.f);
    acc.z += fmaxf(fmaf(s4.z, bf2f(uv.z), t4.z), 0.f);
    acc.w += fmaxf(fmaf(s4.w, bf2f(uv.w), t4.w), 0.f);
  }
  float inv = 1.0f / fmaxf((float)(hi - lo), 1.0f);
  acc.x *= inv; acc.y *= inv; acc.z *= inv; acc.w *= inv;
  *(f4*)(pooled + (size_t)g*HD + c) = acc;
}

// ---------------- head ----------------
__global__ __launch_bounds__(128) void k_head(const float* __restrict__ pooled,
    const float* __restrict__ W1, const float* __restrict__ b1,
    const float* __restrict__ W2, const float* __restrict__ b2, float* __restrict__ out)
{
  __shared__ float p[HD];
  __shared__ float red[2];
  int g = blockIdx.x, t = threadIdx.x;
  if(t < 64) *(f4*)&p[t*4] = *(const f4*)(pooled + (size_t)g*HD + t*4);
  __syncthreads();
  float s = b1[t];
  for(int k=0;k<HD;k++) s = fmaf(p[k], W1[k*128 + t], s);
  float o = fmaxf(s, 0.f) * W2[t];
  #pragma unroll
  for(int d=1; d<64; d<<=1) o += __shfl_xor(o, d, 64);
  if((t & 63) == 0) red[t>>6] = o;
  __syncthreads();
  if(t == 0) out[g] = red[0] + red[1] + b2[0];
}

// ---------------- launch ----------------
extern "C" void kernel_launch(void* const* d_in, const int* in_sizes, int n_in,
                              void* d_out, int out_size, void* d_ws, size_t ws_size,
                              hipStream_t stream) {
  const float* x    = (const float*)d_in[0];
  const int*   ei   = (const int*)  d_in[1];
  const int*   bat  = (const int*)  d_in[2];
  const float* inW  = (const float*)d_in[3];
  const float* inb  = (const float*)d_in[4];
  const float* W1   = (const float*)d_in[5];
  const float* b1   = (const float*)d_in[6];
  const float* g1   = (const float*)d_in[7];
  const float* be1  = (const float*)d_in[8];
  const float* W2   = (const float*)d_in[9];
  const float* b2   = (const float*)d_in[10];
  const float* g2   = (const float*)d_in[11];
  const float* be2  = (const float*)d_in[12];
  const float* eps  = (const float*)d_in[13];
  const float* hW1  = (const float*)d_in[14];
  const float* hb1  = (const float*)d_in[15];
  const float* hW2  = (const float*)d_in[16];
  const float* hb2  = (const float*)d_in[17];
  float* out = (float*)d_out;

  char* p = (char*)d_ws;
  auto alloc = [&](size_t bytes)->char*{
    char* r = p; p += (bytes + 255) & ~(size_t)255; return r;
  };
  unsigned short* B0 = (unsigned short*)alloc((size_t)MPAD*HD*2);
  unsigned short* B1 = (unsigned short*)alloc((size_t)MPAD*HD*2);
  unsigned short* Wtin = (unsigned short*)alloc((size_t)FINDIM*HD*2);
  unsigned short* Wt1  = (unsigned short*)alloc((size_t)NLAYER*HD*HD*2);
  unsigned short* Wt2  = (unsigned short*)alloc((size_t)NLAYER*HD*HD*2);
  int* counts  = (int*)alloc((size_t)NN*4);
  int* offsets = (int*)alloc((size_t)(NN+1)*4);
  int* cursor  = (int*)alloc((size_t)NN*4);
  int* eidx    = (int*)alloc((size_t)NE*4);
  int* partials= (int*)alloc(128*4);
  float* cs    = (float*)alloc(4*HD*4);
  float* bnp   = (float*)alloc(4*HD*4);
  float* pooled= (float*)alloc((size_t)NG*HD*4);

  // CSR build
  k_zero<<<(NN+255)/256, 256, 0, stream>>>(counts, NN);
  k_count<<<(NE+255)/256, 256, 0, stream>>>(ei, counts);
  int nb = (NN + 1023)/1024;
  k_scan_partial<<<nb, 256, 0, stream>>>(counts, partials);
  k_scan_tot<<<1, 128, 0, stream>>>(partials, offsets, nb);
  k_scan_final<<<nb, 256, 0, stream>>>(counts, partials, offsets, cursor);
  k_fill<<<(NE+255)/256, 256, 0, stream>>>(ei, cursor, eidx);

  // weights -> bf16 [n][k]
  k_wt<<<dim3((FINDIM*HD+255)/256, 1), 256, 0, stream>>>(inW, Wtin, FINDIM, HD);
  k_wt<<<dim3((HD*HD+255)/256, NLAYER), 256, 0, stream>>>(W1, Wt1, HD, HD);
  k_wt<<<dim3((HD*HD+255)/256, NLAYER), 256, 0, stream>>>(W2, Wt2, HD, HD);

  // zero pad rows of B1 once (B0's pad established by gemm_in epilogue)
  {
    int padInts = (MPAD - NN) * HD / 2;
    k_zero<<<(padInts+255)/256, 256, 0, stream>>>((int*)(B1 + (size_t)NN*HD), padInts);
  }

  k_gemmb_in<<<2*MG, 256, 0, stream>>>(x, Wtin, inb, B0);

  float* sc1 = bnp, *sh1 = bnp + HD, *sc2 = bnp + 2*HD, *sh2 = bnp + 3*HD;
  unsigned short* hbuf = B0;
  unsigned short* tbuf = B1;
  for(int l=0; l<NLAYER; l++){
    k_zero<<<4, 256, 0, stream>>>((int*)cs, 4*HD);
    k_agg<<<(NN+3)/4, 256, 0, stream>>>(hbuf, tbuf, offsets, eidx, eps, l, sc2, sh2, l==0 ? 1 : 0);
    k_gemmb<0, false, true><<<2*MG, 256, 0, stream>>>(tbuf, Wt1 + (size_t)l*HD*HD, b1 + l*HD,
                                                      nullptr, nullptr, hbuf, cs);
    k_bnfin<<<1, HD, 0, stream>>>(cs, b1 + l*HD, g1 + l*HD, be1 + l*HD, sc1, sh1);
    k_gemmb<1, false, true><<<2*MG, 256, 0, stream>>>(hbuf, Wt2 + (size_t)l*HD*HD, b2 + l*HD,
                                                      sc1, sh1, tbuf, cs + 2*HD);
    k_bnfin<<<1, HD, 0, stream>>>(cs + 2*HD, b2 + l*HD, g2 + l*HD, be2 + l*HD, sc2, sh2);
    unsigned short* tmp = hbuf; hbuf = tbuf; tbuf = tmp;
  }

  k_pool<<<(NG+3)/4, 256, 0, stream>>>(hbuf, bat, sc2, sh2, pooled);
  k_head<<<NG, 128, 0, stream>>>(pooled, hW1, hb1, hW2, hb2, out);
}

// Round 10
// 1012.141 us; speedup vs baseline: 1.0248x; 1.0248x over previous
//
#include <hip/hip_runtime.h>
#include <hip/hip_bf16.h>
#include <stdint.h>
#include <stddef.h>

#define NN 100000
#define NE 300000
#define FINDIM 128
#define HD 256
#define NG 4000
#define NLAYER 5
#define MPAD 100096   // 32*3128; pad rows kept == 0.0f always
#define NT (MPAD/32)  // 3128 m-tiles of 32 rows
#define MGB 384       // m-groups for k_gemmb (grid 2*MGB) — r8 champion config
#define MGF 512       // m-groups for fused kernel (grid MGF, 512-thread blocks)

typedef __attribute__((ext_vector_type(8))) short bf8;
typedef __attribute__((ext_vector_type(4))) float f4;

#define FENCE() __asm__ volatile("" ::: "memory")
#define WAITVM0() __asm__ volatile("s_waitcnt vmcnt(0)" ::: "memory")
#define WAITVM4() __asm__ volatile("s_waitcnt vmcnt(4)" ::: "memory")
#define WAITVM6() __asm__ volatile("s_waitcnt vmcnt(6)" ::: "memory")
#define WAITLGKM() __asm__ volatile("s_waitcnt lgkmcnt(0)" ::: "memory")
#define BARRIER() do { FENCE(); __builtin_amdgcn_s_barrier(); FENCE(); } while(0)

__device__ __forceinline__ unsigned short f2bf(float f){
  union { float f; unsigned u; } uf; uf.f = f;
  unsigned r = uf.u + 0x7fffu + ((uf.u >> 16) & 1u);
  return (unsigned short)(r >> 16);
}
__device__ __forceinline__ float bf2f(unsigned short h){
  union { unsigned u; float f; } uf; uf.u = ((unsigned)h) << 16; return uf.f;
}

__device__ __forceinline__ void gload16(const void* g, void* l){
  __builtin_amdgcn_global_load_lds((const __attribute__((address_space(1))) void*)g,
                                   (__attribute__((address_space(3))) void*)l, 16, 0, 0);
}

// ---------------- zero fill ----------------
__global__ void k_zero(int* __restrict__ p, int n){
  int i = blockIdx.x*256 + threadIdx.x;
  if(i < n) p[i] = 0;
}

// ---------------- CSR build ----------------
__global__ void k_count(const int* __restrict__ ei, int* __restrict__ counts){
  int e = blockIdx.x*256 + threadIdx.x;
  if(e < NE) atomicAdd(&counts[ei[NE + e]], 1);
}

__global__ void k_scan_partial(const int* __restrict__ counts, int* __restrict__ partials){
  __shared__ int sw[4];
  int b = blockIdx.x, t = threadIdx.x;
  int base = b*1024 + t*4;
  int s = 0;
  #pragma unroll
  for(int j=0;j<4;j++){ int i = base+j; if(i < NN) s += counts[i]; }
  #pragma unroll
  for(int d=1; d<64; d<<=1) s += __shfl_xor(s, d, 64);
  if((t & 63) == 0) sw[t>>6] = s;
  __syncthreads();
  if(t == 0) partials[b] = sw[0]+sw[1]+sw[2]+sw[3];
}

__global__ void k_scan_tot(int* __restrict__ partials, int* __restrict__ offsets, int nb){
  __shared__ int sm[128];
  int t = threadIdx.x;
  int v = (t < nb) ? partials[t] : 0;
  sm[t] = v; __syncthreads();
  for(int d=1; d<128; d<<=1){
    int x = 0;
    if(t >= d) x = sm[t-d];
    __syncthreads();
    sm[t] += x;
    __syncthreads();
  }
  if(t < nb) partials[t] = sm[t] - v;   // exclusive
  if(t == 127) offsets[NN] = sm[127];   // total == NE
}

__global__ void k_scan_final(const int* __restrict__ counts, const int* __restrict__ partials,
                             int* __restrict__ offsets, int* __restrict__ cursor){
  __shared__ int wsum[4];
  int b = blockIdx.x, t = threadIdx.x;
  int base = b*1024 + t*4;
  int c[4]; int ts = 0;
  #pragma unroll
  for(int j=0;j<4;j++){ int i = base+j; c[j] = (i < NN) ? counts[i] : 0; ts += c[j]; }
  int lane = t & 63;
  int inc = ts;
  #pragma unroll
  for(int d=1; d<64; d<<=1){ int x = __shfl_up(inc, d, 64); if(lane >= d) inc += x; }
  if(lane == 63) wsum[t>>6] = inc;
  __syncthreads();
  int woff = 0;
  for(int w2=0; w2<(t>>6); w2++) woff += wsum[w2];
  int excl = partials[b] + woff + inc - ts;
  #pragma unroll
  for(int j=0;j<4;j++){
    int i = base+j;
    if(i < NN){ offsets[i] = excl; cursor[i] = excl; excl += c[j]; }
  }
}

__global__ void k_fill(const int* __restrict__ ei, int* __restrict__ cursor, int* __restrict__ eidx){
  int e = blockIdx.x*256 + threadIdx.x;
  if(e < NE){
    int d = ei[NE + e];
    int pos = atomicAdd(&cursor[d], 1);
    eidx[pos] = ei[e];
  }
}

// ---------------- weight transpose/convert ----------------
__global__ void k_wt(const float* __restrict__ src, unsigned short* __restrict__ dst, int K, int Ncols){
  int l = blockIdx.y;
  size_t base = (size_t)l * K * Ncols;
  int i = blockIdx.x*256 + threadIdx.x;
  if(i < K*Ncols){
    int k = i / Ncols, n = i % Ncols;
    dst[base + (size_t)n*K + k] = f2bf(src[base + i]);
  }
}

// ---------------- act helper ----------------
__device__ __forceinline__ f4 act4(ushort4 uv, f4 s4, f4 t4, int ident){
  f4 u;
  u.x = bf2f(uv.x); u.y = bf2f(uv.y); u.z = bf2f(uv.z); u.w = bf2f(uv.w);
  if(!ident){
    u.x = fmaxf(fmaf(s4.x, u.x, t4.x), 0.f);
    u.y = fmaxf(fmaf(s4.y, u.y, t4.y), 0.f);
    u.z = fmaxf(fmaf(s4.z, u.z, t4.z), 0.f);
    u.w = fmaxf(fmaf(s4.w, u.w, t4.w), 0.f);
  }
  return u;
}

// ---------------- FUSED agg + GEMM1: C = [(1+eps)*act(h) + gather-sum(act(h))] @ W1^T + b1 ----------------
// Grid MGF blocks x 512 thr (8 waves). Wave tile 32m x 32n (nbase = w*32, covers all 256 cols).
// Per 32-row tile: waves gather 4 rows each (act applied, f32 sum), pack bf16 into
// XOR-swizzled LDS A-tile; barrier; pure LDS+MFMA with B-in-regs. Q never hits HBM.
template<int IDENT>
__global__ __launch_bounds__(512) void k_gfuse(
    const unsigned short* __restrict__ h, const unsigned short* __restrict__ Bt,
    const float* __restrict__ bias, const float* __restrict__ sc,
    const float* __restrict__ sh, const float* __restrict__ eps, int l,
    const int* __restrict__ offs, const int* __restrict__ eidx,
    unsigned short* __restrict__ C, float* __restrict__ stats)
{
  __shared__ __align__(16) unsigned short As[2][8192];   // 2 x (32 rows x 256 k) = 32 KB
  __shared__ __align__(16) unsigned short Cs[8][1152];   // 18 KB epilogue scratch
  const int t = threadIdx.x;
  const int lane = t & 63, w = t >> 6;      // w: 0..7
  const int q = lane >> 4, ln = lane & 15;
  const int mg = blockIdx.x;
  const int nbase = w*32;
  const int gc = lane*4;                     // gather col base (0..252)

  f4 s4 = (f4){0.f,0.f,0.f,0.f}, t4 = (f4){0.f,0.f,0.f,0.f};
  if(!IDENT){ s4 = *(const f4*)(sc + gc); t4 = *(const f4*)(sh + gc); }
  const float ep = 1.f + eps[l];

  // B fragments resident in registers (L2-resident 128 KB weight)
  bf8 bb[2][8];
  #pragma unroll
  for(int nf=0; nf<2; nf++)
    #pragma unroll
    for(int s=0; s<8; s++)
      bb[nf][s] = *(const bf8*)(Bt + (size_t)(nbase + nf*16 + ln)*HD + s*32 + q*8);

  float bv[2];
  #pragma unroll
  for(int nf=0; nf<2; nf++) bv[nf] = bias[nbase + nf*16 + ln];

  auto gather = [&](int mt, int b){
    unsigned short* Ab = &As[b][0];
    const int m0 = mt*32;
    if(m0 >= NN){
      *(uint4*)&Ab[t*16]     = (uint4){0u,0u,0u,0u};
      *(uint4*)&Ab[t*16 + 8] = (uint4){0u,0u,0u,0u};
      return;
    }
    #pragma unroll
    for(int rr=0; rr<4; rr++){
      const int r = w*4 + rr;
      const int n = m0 + r;
      f4 a = act4(*(const ushort4*)(h + (size_t)n*HD + gc), s4, t4, IDENT);
      f4 acc;
      acc.x = ep*a.x; acc.y = ep*a.y; acc.z = ep*a.z; acc.w = ep*a.w;
      int lo = offs[n], hi = offs[n+1];
      for(int base = lo; base < hi; base += 64){
        int rem = hi - base; if(rem > 64) rem = 64;
        int idxv = 0;
        if(base + lane < hi) idxv = eidx[base + lane];
        int j = 0;
        for(; j + 4 <= rem; j += 4){
          int s0 = __shfl(idxv, j, 64),   s1 = __shfl(idxv, j+1, 64);
          int s2 = __shfl(idxv, j+2, 64), s3 = __shfl(idxv, j+3, 64);
          ushort4 u0 = *(const ushort4*)(h + (size_t)s0*HD + gc);
          ushort4 u1 = *(const ushort4*)(h + (size_t)s1*HD + gc);
          ushort4 u2 = *(const ushort4*)(h + (size_t)s2*HD + gc);
          ushort4 u3 = *(const ushort4*)(h + (size_t)s3*HD + gc);
          f4 a0 = act4(u0, s4, t4, IDENT), a1 = act4(u1, s4, t4, IDENT);
          f4 a2 = act4(u2, s4, t4, IDENT), a3 = act4(u3, s4, t4, IDENT);
          acc.x += (a0.x + a1.x) + (a2.x + a3.x);
          acc.y += (a0.y + a1.y) + (a2.y + a3.y);
          acc.z += (a0.z + a1.z) + (a2.z + a3.z);
          acc.w += (a0.w + a1.w) + (a2.w + a3.w);
        }
        for(; j < rem; j++){
          int s0 = __shfl(idxv, j, 64);
          f4 a0 = act4(*(const ushort4*)(h + (size_t)s0*HD + gc), s4, t4, IDENT);
          acc.x += a0.x; acc.y += a0.y; acc.z += a0.z; acc.w += a0.w;
        }
      }
      // pack + store to swizzled A-tile: chunk cc=lane>>1 at p = cc ^ (r&7), half = lane&1
      ushort4 o;
      o.x = f2bf(acc.x); o.y = f2bf(acc.y); o.z = f2bf(acc.z); o.w = f2bf(acc.w);
      int p = (lane >> 1) ^ (r & 7);
      *(ushort4*)&Ab[r*256 + p*8 + (lane & 1)*4] = o;
    }
  };

  float sacc[2] = {0.f, 0.f}, ssacc[2] = {0.f, 0.f};

  gather(mg, 0);
  __syncthreads();

  int tc = 0;
  for(int mt = mg; mt < NT; mt += MGF, tc++){
    const unsigned short* Ab = &As[tc&1][0];
    const int m0 = mt*32;
    const bool padt = (m0 >= NN);

    f4 acc[2][2];
    #pragma unroll
    for(int i=0;i<2;i++)
      #pragma unroll
      for(int j=0;j<2;j++) acc[i][j] = (f4){0.f,0.f,0.f,0.f};

    #pragma unroll
    for(int s=0; s<8; s++){
      bf8 af[2];
      #pragma unroll
      for(int mi=0; mi<2; mi++){
        int row = mi*16 + ln;
        int p = (s*4 + q) ^ (row & 7);
        af[mi] = *(const bf8*)&Ab[row*256 + p*8];
      }
      #pragma unroll
      for(int mi=0; mi<2; mi++)
        #pragma unroll
        for(int nf=0; nf<2; nf++)
          acc[mi][nf] = __builtin_amdgcn_mfma_f32_16x16x32_bf16(af[mi], bb[nf][s], acc[mi][nf], 0, 0, 0);
    }

    #pragma unroll
    for(int nf=0; nf<2; nf++)
      #pragma unroll
      for(int mi=0; mi<2; mi++)
        #pragma unroll
        for(int r=0; r<4; r++){
          float v = acc[mi][nf][r];
          sacc[nf] += v; ssacc[nf] = fmaf(v, v, ssacc[nf]);
        }

    // epilogue: per-wave LDS transpose -> coalesced 16B row stores (pre-BN, bias added)
    unsigned short* wsc = &Cs[w][0];     // 32 rows x 36
    #pragma unroll
    for(int mi=0; mi<2; mi++)
      #pragma unroll
      for(int nf=0; nf<2; nf++)
        #pragma unroll
        for(int r=0; r<4; r++){
          float v = acc[mi][nf][r] + bv[nf];
          if(padt) v = 0.f;
          wsc[(mi*16 + q*4 + r)*36 + nf*16 + ln] = f2bf(v);
        }
    {
      int r2 = lane >> 1, ch = lane & 1;
      size_t cb = (size_t)(m0 + r2)*HD + w*32;
      uint4 u0 = *(const uint4*)&wsc[r2*36 + ch*8];
      uint4 u1 = *(const uint4*)&wsc[r2*36 + (ch+2)*8];
      *(uint4*)&C[cb + ch*8]     = u0;
      *(uint4*)&C[cb + (ch+2)*8] = u1;
    }

    // gather next tile into the other buffer (overlaps other blocks' MFMA)
    if(mt + MGF < NT) gather(mt + MGF, (tc+1)&1);
    __syncthreads();
  }

  #pragma unroll
  for(int nf=0; nf<2; nf++){
    float s = sacc[nf], ss = ssacc[nf];
    s  += __shfl_xor(s, 16, 64);  s  += __shfl_xor(s, 32, 64);
    ss += __shfl_xor(ss, 16, 64); ss += __shfl_xor(ss, 32, 64);
    if(q == 0){
      int gn = nbase + nf*16 + ln;
      atomicAdd(&stats[gn], s);
      atomicAdd(&stats[HD + gn], ss);
    }
  }
}

// ---------------- GEMM (r8 champion): B-in-regs + manual per-tile DMA pipeline ----------------
template<int TRANS, bool RELUOUT, bool STATS>
__global__ __launch_bounds__(256, 3) void k_gemmb(
    const unsigned short* __restrict__ A, const unsigned short* __restrict__ Bt,
    const float* __restrict__ bias, const float* __restrict__ preS,
    const float* __restrict__ preT, unsigned short* __restrict__ C,
    float* __restrict__ stats)
{
  __shared__ __align__(16) unsigned short As[2][8192];   // 32 KB
  __shared__ __align__(16) unsigned short Cs[4][1152];   // 9 KB
  __shared__ __align__(16) float SP[512];                // 2 KB
  const int t = threadIdx.x;
  const int lane = t & 63, w = t >> 6;
  const int q = lane >> 4, ln = lane & 15;
  const int nh = blockIdx.x & 1;
  const int mg = blockIdx.x >> 1;
  const int nbase = nh*128 + w*32;

  if(TRANS){ SP[t] = preS[t]; SP[256 + t] = preT[t]; WAITLGKM(); }

  bf8 bb[2][8];
  #pragma unroll
  for(int nf=0; nf<2; nf++)
    #pragma unroll
    for(int s=0; s<8; s++)
      bb[nf][s] = *(const bf8*)(Bt + (size_t)(nbase + nf*16 + ln)*HD + s*32 + q*8);

  float bv[2];
  #pragma unroll
  for(int nf=0; nf<2; nf++) bv[nf] = bias[nbase + nf*16 + ln];

  auto issueA = [&](int mt, int b){
    const int m0 = mt*32;
    #pragma unroll
    for(int j=0; j<4; j++){
      int slot = j*256 + t;
      int row = slot >> 5, p = slot & 31;
      int c = p ^ (row & 7);
      gload16(A + (size_t)(m0 + row)*HD + c*8, &As[b][(j*256 + w*64)*8]);
    }
  };

  float sacc[2] = {0.f, 0.f}, ssacc[2] = {0.f, 0.f};

  issueA(mg, 0);
  issueA(mg + MGB, 1);

  int tc = 0;
  for(int mt = mg; mt < NT; mt += MGB, tc++){
    const bool last = (mt + MGB >= NT);
    if(last)           WAITVM0();
    else if(tc == 0)   WAITVM4();
    else               WAITVM6();
    BARRIER();

    unsigned short* Ab = &As[tc&1][0];
    const int m0 = mt*32;
    const bool padt = (m0 >= NN);

    if(TRANS){
      #pragma unroll
      for(int j=0; j<4; j++){
        int slot = j*256 + t;
        if(padt){
          *(uint4*)&Ab[slot*8] = (uint4){0u,0u,0u,0u};
        } else {
          int row = slot >> 5, p = slot & 31;
          int c = p ^ (row & 7);
          uint4 u = *(const uint4*)&Ab[slot*8];
          f4 s0 = *(const f4*)&SP[c*8];
          f4 s1 = *(const f4*)&SP[c*8 + 4];
          f4 t0 = *(const f4*)&SP[256 + c*8];
          f4 t1 = *(const f4*)&SP[256 + c*8 + 4];
          float scv[8] = {s0.x,s0.y,s0.z,s0.w,s1.x,s1.y,s1.z,s1.w};
          float shv[8] = {t0.x,t0.y,t0.z,t0.w,t1.x,t1.y,t1.z,t1.w};
          unsigned short* us = (unsigned short*)&u;
          #pragma unroll
          for(int e=0; e<8; e++){
            float v = bf2f(us[e]);
            v = fmaxf(fmaf(scv[e], v, shv[e]), 0.f);
            us[e] = f2bf(v);
          }
          *(uint4*)&Ab[slot*8] = u;
        }
      }
      WAITLGKM();
      BARRIER();
    }

    f4 acc[2][2];
    #pragma unroll
    for(int i=0;i<2;i++)
      #pragma unroll
      for(int j=0;j<2;j++) acc[i][j] = (f4){0.f,0.f,0.f,0.f};

    #pragma unroll
    for(int s=0; s<8; s++){
      bf8 af[2];
      #pragma unroll
      for(int mi=0; mi<2; mi++){
        int row = mi*16 + ln;
        int p = (s*4 + q) ^ (row & 7);
        af[mi] = *(const bf8*)&Ab[row*256 + p*8];
      }
      #pragma unroll
      for(int mi=0; mi<2; mi++)
        #pragma unroll
        for(int nf=0; nf<2; nf++)
          acc[mi][nf] = __builtin_amdgcn_mfma_f32_16x16x32_bf16(af[mi], bb[nf][s], acc[mi][nf], 0, 0, 0);
    }

    if(STATS){
      #pragma unroll
      for(int nf=0; nf<2; nf++)
        #pragma unroll
        for(int mi=0; mi<2; mi++)
          #pragma unroll
          for(int r=0; r<4; r++){
            float v = acc[mi][nf][r];
            sacc[nf] += v; ssacc[nf] = fmaf(v, v, ssacc[nf]);
          }
    }

    unsigned short* wsc = &Cs[w][0];     // 32 rows x 36
    #pragma unroll
    for(int mi=0; mi<2; mi++)
      #pragma unroll
      for(int nf=0; nf<2; nf++)
        #pragma unroll
        for(int r=0; r<4; r++){
          float v = acc[mi][nf][r] + bv[nf];
          if(RELUOUT) v = fmaxf(v, 0.f);
          if(padt) v = 0.f;
          wsc[(mi*16 + q*4 + r)*36 + nf*16 + ln] = f2bf(v);
        }
    {
      int r2 = lane >> 1, ch = lane & 1;
      size_t cb = (size_t)(m0 + r2)*HD + nh*128 + w*32;
      uint4 u0 = *(const uint4*)&wsc[r2*36 + ch*8];
      uint4 u1 = *(const uint4*)&wsc[r2*36 + (ch+2)*8];
      *(uint4*)&C[cb + ch*8]     = u0;
      *(uint4*)&C[cb + (ch+2)*8] = u1;
    }

    WAITLGKM();
    BARRIER();
    if(mt + 2*MGB < NT) issueA(mt + 2*MGB, tc&1);
  }

  if(STATS){
    #pragma unroll
    for(int nf=0; nf<2; nf++){
      float s = sacc[nf], ss = ssacc[nf];
      s  += __shfl_xor(s, 16, 64);  s  += __shfl_xor(s, 32, 64);
      ss += __shfl_xor(ss, 16, 64); ss += __shfl_xor(ss, 32, 64);
      if(q == 0){
        int gn = nbase + nf*16 + ln;
        atomicAdd(&stats[gn], s);
        atomicAdd(&stats[HD + gn], ss);
      }
    }
  }
}

// ---------------- input projection (f32 A, K=128), B-in-registers (r8) ----------------
__global__ __launch_bounds__(256, 3) void k_gemmb_in(
    const float* __restrict__ A, const unsigned short* __restrict__ Bt,
    const float* __restrict__ bias, unsigned short* __restrict__ C)
{
  __shared__ __align__(16) unsigned short As[4096];      // 8 KB
  __shared__ __align__(16) unsigned short Cs[4][1152];
  const int t = threadIdx.x;
  const int lane = t & 63, w = t >> 6;
  const int q = lane >> 4, ln = lane & 15;
  const int nh = blockIdx.x & 1;
  const int mg = blockIdx.x >> 1;
  const int nbase = nh*128 + w*32;

  bf8 bb[2][4];
  #pragma unroll
  for(int nf=0; nf<2; nf++)
    #pragma unroll
    for(int s=0; s<4; s++)
      bb[nf][s] = *(const bf8*)(Bt + (size_t)(nbase + nf*16 + ln)*FINDIM + s*32 + q*8);

  float bv[2];
  #pragma unroll
  for(int nf=0; nf<2; nf++) bv[nf] = bias[nbase + nf*16 + ln];

  for(int mt = mg; mt < NT; mt += MGB){
    const int m0 = mt*32;
    const bool padt = (m0 >= NN);
    __syncthreads();
    #pragma unroll
    for(int j=0; j<2; j++){
      int slot = j*256 + t;
      int row = slot >> 4, p = slot & 15;
      int c = p ^ (row & 7);
      int gm = m0 + row;
      f4 v0 = (f4){0.f,0.f,0.f,0.f}, v1 = (f4){0.f,0.f,0.f,0.f};
      if(gm < NN){
        v0 = *(const f4*)&A[(size_t)gm*FINDIM + c*8];
        v1 = *(const f4*)&A[(size_t)gm*FINDIM + c*8 + 4];
      }
      ushort4 a0, a1;
      a0.x = f2bf(v0.x); a0.y = f2bf(v0.y); a0.z = f2bf(v0.z); a0.w = f2bf(v0.w);
      a1.x = f2bf(v1.x); a1.y = f2bf(v1.y); a1.z = f2bf(v1.z); a1.w = f2bf(v1.w);
      *(ushort4*)&As[row*128 + p*8]     = a0;
      *(ushort4*)&As[row*128 + p*8 + 4] = a1;
    }
    __syncthreads();

    f4 acc[2][2];
    #pragma unroll
    for(int i=0;i<2;i++)
      #pragma unroll
      for(int j=0;j<2;j++) acc[i][j] = (f4){0.f,0.f,0.f,0.f};

    #pragma unroll
    for(int s=0; s<4; s++){
      bf8 af[2];
      #pragma unroll
      for(int mi=0; mi<2; mi++){
        int row = mi*16 + ln;
        int p = (s*4 + q) ^ (row & 7);
        af[mi] = *(const bf8*)&As[row*128 + p*8];
      }
      #pragma unroll
      for(int mi=0; mi<2; mi++)
        #pragma unroll
        for(int nf=0; nf<2; nf++)
          acc[mi][nf] = __builtin_amdgcn_mfma_f32_16x16x32_bf16(af[mi], bb[nf][s], acc[mi][nf], 0, 0, 0);
    }

    unsigned short* wsc = &Cs[w][0];
    #pragma unroll
    for(int mi=0; mi<2; mi++)
      #pragma unroll
      for(int nf=0; nf<2; nf++)
        #pragma unroll
        for(int r=0; r<4; r++){
          float v = fmaxf(acc[mi][nf][r] + bv[nf], 0.f);
          if(padt) v = 0.f;
          wsc[(mi*16 + q*4 + r)*36 + nf*16 + ln] = f2bf(v);
        }
    int r2 = lane >> 1, ch = lane & 1;
    size_t cb = (size_t)(m0 + r2)*HD + nh*128 + w*32;
    uint4 u0 = *(const uint4*)&wsc[r2*36 + ch*8];
    uint4 u1 = *(const uint4*)&wsc[r2*36 + (ch+2)*8];
    *(uint4*)&C[cb + ch*8]     = u0;
    *(uint4*)&C[cb + (ch+2)*8] = u1;
  }
}

// ---------------- BN finalize (bias folded: stats are bias-free raw sums) ----------------
__global__ void k_bnfin(const float* __restrict__ cs, const float* __restrict__ bias,
                        const float* __restrict__ g, const float* __restrict__ be,
                        float* __restrict__ sc, float* __restrict__ sh){
  int c = threadIdx.x;
  float m0 = cs[c] * (1.0f/NN);
  float mean = m0 + bias[c];
  float var  = cs[HD + c] * (1.0f/NN) - m0*m0;
  float s = g[c] * rsqrtf(var + 1e-5f);
  sc[c] = s;
  sh[c] = be[c] - mean*s;
}

// ---------------- pooling ----------------
__device__ __forceinline__ int lowb(const int* __restrict__ arr, int n, int key){
  int lo = 0, hi = n;
  while(lo < hi){ int mid = (lo + hi) >> 1; if(arr[mid] < key) lo = mid + 1; else hi = mid; }
  return lo;
}

__global__ __launch_bounds__(256) void k_pool(const unsigned short* __restrict__ src,
    const int* __restrict__ batch,
    const float* __restrict__ sc, const float* __restrict__ sh, float* __restrict__ pooled)
{
  int wv = threadIdx.x >> 6;
  int g = blockIdx.x*4 + wv;
  if(g >= NG) return;
  int lane = threadIdx.x & 63;
  int c = lane << 2;
  int lo = lowb(batch, NN, g);
  int hi = lowb(batch, NN, g+1);
  f4 s4 = *(const f4*)(sc + c);
  f4 t4 = *(const f4*)(sh + c);
  f4 acc = (f4){0.f,0.f,0.f,0.f};
  for(int n=lo; n<hi; n++){
    ushort4 uv = *(const ushort4*)(src + (size_t)n*HD + c);
    acc.x += fmaxf(fmaf(s4.x, bf2f(uv.x), t4.x), 0.f);
    acc.y += fmaxf(fmaf(s4.y, bf2f(uv.y), t4.y), 0.f);
    acc.z += fmaxf(fmaf(s4.z, bf2f(uv.z), t4.z), 0.f);
    acc.w += fmaxf(fmaf(s4.w, bf2f(uv.w), t4.w), 0.f);
  }
  float inv = 1.0f / fmaxf((float)(hi - lo), 1.0f);
  acc.x *= inv; acc.y *= inv; acc.z *= inv; acc.w *= inv;
  *(f4*)(pooled + (size_t)g*HD + c) = acc;
}

// ---------------- head ----------------
__global__ __launch_bounds__(128) void k_head(const float* __restrict__ pooled,
    const float* __restrict__ W1, const float* __restrict__ b1,
    const float* __restrict__ W2, const float* __restrict__ b2, float* __restrict__ out)
{
  __shared__ float p[HD];
  __shared__ float red[2];
  int g = blockIdx.x, t = threadIdx.x;
  if(t < 64) *(f4*)&p[t*4] = *(const f4*)(pooled + (size_t)g*HD + t*4);
  __syncthreads();
  float s = b1[t];
  for(int k=0;k<HD;k++) s = fmaf(p[k], W1[k*128 + t], s);
  float o = fmaxf(s, 0.f) * W2[t];
  #pragma unroll
  for(int d=1; d<64; d<<=1) o += __shfl_xor(o, d, 64);
  if((t & 63) == 0) red[t>>6] = o;
  __syncthreads();
  if(t == 0) out[g] = red[0] + red[1] + b2[0];
}

// ---------------- launch ----------------
extern "C" void kernel_launch(void* const* d_in, const int* in_sizes, int n_in,
                              void* d_out, int out_size, void* d_ws, size_t ws_size,
                              hipStream_t stream) {
  const float* x    = (const float*)d_in[0];
  const int*   ei   = (const int*)  d_in[1];
  const int*   bat  = (const int*)  d_in[2];
  const float* inW  = (const float*)d_in[3];
  const float* inb  = (const float*)d_in[4];
  const float* W1   = (const float*)d_in[5];
  const float* b1   = (const float*)d_in[6];
  const float* g1   = (const float*)d_in[7];
  const float* be1  = (const float*)d_in[8];
  const float* W2   = (const float*)d_in[9];
  const float* b2   = (const float*)d_in[10];
  const float* g2   = (const float*)d_in[11];
  const float* be2  = (const float*)d_in[12];
  const float* eps  = (const float*)d_in[13];
  const float* hW1  = (const float*)d_in[14];
  const float* hb1  = (const float*)d_in[15];
  const float* hW2  = (const float*)d_in[16];
  const float* hb2  = (const float*)d_in[17];
  float* out = (float*)d_out;

  char* p = (char*)d_ws;
  auto alloc = [&](size_t bytes)->char*{
    char* r = p; p += (bytes + 255) & ~(size_t)255; return r;
  };
  unsigned short* B0 = (unsigned short*)alloc((size_t)MPAD*HD*2);
  unsigned short* B1 = (unsigned short*)alloc((size_t)MPAD*HD*2);
  unsigned short* Wtin = (unsigned short*)alloc((size_t)FINDIM*HD*2);
  unsigned short* Wt1  = (unsigned short*)alloc((size_t)NLAYER*HD*HD*2);
  unsigned short* Wt2  = (unsigned short*)alloc((size_t)NLAYER*HD*HD*2);
  int* counts  = (int*)alloc((size_t)NN*4);
  int* offsets = (int*)alloc((size_t)(NN+1)*4);
  int* cursor  = (int*)alloc((size_t)NN*4);
  int* eidx    = (int*)alloc((size_t)NE*4);
  int* partials= (int*)alloc(128*4);
  float* cs    = (float*)alloc(4*HD*4);
  float* bnp   = (float*)alloc(4*HD*4);
  float* pooled= (float*)alloc((size_t)NG*HD*4);

  // CSR build
  k_zero<<<(NN+255)/256, 256, 0, stream>>>(counts, NN);
  k_count<<<(NE+255)/256, 256, 0, stream>>>(ei, counts);
  int nb = (NN + 1023)/1024;
  k_scan_partial<<<nb, 256, 0, stream>>>(counts, partials);
  k_scan_tot<<<1, 128, 0, stream>>>(partials, offsets, nb);
  k_scan_final<<<nb, 256, 0, stream>>>(counts, partials, offsets, cursor);
  k_fill<<<(NE+255)/256, 256, 0, stream>>>(ei, cursor, eidx);

  // weights -> bf16 [n][k]
  k_wt<<<dim3((FINDIM*HD+255)/256, 1), 256, 0, stream>>>(inW, Wtin, FINDIM, HD);
  k_wt<<<dim3((HD*HD+255)/256, NLAYER), 256, 0, stream>>>(W1, Wt1, HD, HD);
  k_wt<<<dim3((HD*HD+255)/256, NLAYER), 256, 0, stream>>>(W2, Wt2, HD, HD);

  // zero pad rows of B1 once (B0's pad established by gemm_in epilogue)
  {
    int padInts = (MPAD - NN) * HD / 2;
    k_zero<<<(padInts+255)/256, 256, 0, stream>>>((int*)(B1 + (size_t)NN*HD), padInts);
  }

  k_gemmb_in<<<2*MGB, 256, 0, stream>>>(x, Wtin, inb, B0);

  float* sc1 = bnp, *sh1 = bnp + HD, *sc2 = bnp + 2*HD, *sh2 = bnp + 3*HD;
  // hbuf = B0 (layer input, pre-BN repr), tbuf = B1 (GEMM1 output scratch)
  for(int l=0; l<NLAYER; l++){
    k_zero<<<4, 256, 0, stream>>>((int*)cs, 4*HD);
    // fused agg + GEMM1: B0 -> B1 (pre-BN1), stats -> cs[0:2H]
    if(l == 0)
      k_gfuse<1><<<MGF, 512, 0, stream>>>(B0, Wt1 + (size_t)l*HD*HD, b1 + l*HD,
                                          sc2, sh2, eps, l, offsets, eidx, B1, cs);
    else
      k_gfuse<0><<<MGF, 512, 0, stream>>>(B0, Wt1 + (size_t)l*HD*HD, b1 + l*HD,
                                          sc2, sh2, eps, l, offsets, eidx, B1, cs);
    k_bnfin<<<1, HD, 0, stream>>>(cs, b1 + l*HD, g1 + l*HD, be1 + l*HD, sc1, sh1);
    // GEMM2: B1 (TRANS with BN1) -> B0 (pre-BN2), stats -> cs[2H:4H]
    k_gemmb<1, false, true><<<2*MGB, 256, 0, stream>>>(B1, Wt2 + (size_t)l*HD*HD, b2 + l*HD,
                                                       sc1, sh1, B0, cs + 2*HD);
    k_bnfin<<<1, HD, 0, stream>>>(cs + 2*HD, b2 + l*HD, g2 + l*HD, be2 + l*HD, sc2, sh2);
  }

  k_pool<<<(NG+3)/4, 256, 0, stream>>>(B0, bat, sc2, sh2, pooled);
  k_head<<<NG, 128, 0, stream>>>(pooled, hW1, hb1, hW2, hb2, out);
}